// Round 1
// baseline (17.474 us; speedup 1.0000x reference)
//
#include <hip/hip_runtime.h>
#include <math.h>

#define NN 32   // atoms
#define NP 40   // symmetry params

// Rs = {0.5,1.17,1.83,2.5,3.17}/BOHR computed in double then truncated to f32,
// matching numpy f64 -> jnp f32 cast.
#define BOHR_D 0.52917721092

__global__ __launch_bounds__(256) void angsym_kernel(
    const float* __restrict__ d_cutoff,   // (B,N,N)
    const float* __restrict__ d,          // (B,N,N)
    const float* __restrict__ coords,     // (B,N,3)
    float* __restrict__ out)              // (B,N,40)
{
    __shared__ float cxyz[NN * 3];
    __shared__ float vx[NN], vy[NN], vz[NN];
    __shared__ float drow[NN], frow[NN];
    __shared__ float red[4 * NP];

    const int bi = blockIdx.x;            // b*32 + i
    const int b  = bi >> 5;
    const int i  = bi & 31;
    const int tid = threadIdx.x;

    // Stage batch coords and the i-th rows of d / d_cutoff.
    if (tid < NN * 3)                cxyz[tid]       = coords[b * NN * 3 + tid];
    if (tid >= 128 && tid < 128+NN)  drow[tid - 128] = d[(b * NN + i) * NN + (tid - 128)];
    if (tid >= 192 && tid < 192+NN)  frow[tid - 192] = d_cutoff[(b * NN + i) * NN + (tid - 192)];
    __syncthreads();

    if (tid < NN) {
        vx[tid] = cxyz[i * 3 + 0] - cxyz[tid * 3 + 0];
        vy[tid] = cxyz[i * 3 + 1] - cxyz[tid * 3 + 1];
        vz[tid] = cxyz[i * 3 + 2] - cxyz[tid * 3 + 2];
    }
    __syncthreads();

    // cos/sin of the f32 theta offsets {0, 1.57f, 3.14f, 4.71f}
    const float C1 = (float)0.00079632671073326442;  // cos(1.57f)
    const float S1 = (float)0.99999968293183461;     // sin(1.57f)
    const float C2 = (float)-0.99999873172753954;    // cos(3.14f)
    const float S2 = (float)0.0015926529164868282;   // sin(3.14f)
    const float C3 = (float)-0.0023889083720362966;  // cos(4.71f)
    const float S3 = (float)-0.99999714638771537;    // sin(4.71f)

    const float RS[5] = {
        (float)(0.5  / BOHR_D),
        (float)(1.17 / BOHR_D),
        (float)(1.83 / BOHR_D),
        (float)(2.5  / BOHR_D),
        (float)(3.17 / BOHR_D)
    };
    const float ITA = 1.12f;

    float acc[NP];
    #pragma unroll
    for (int p = 0; p < NP; ++p) acc[p] = 0.f;

    // 1024 (j,k) pairs, 256 threads -> 4 pairs each.
    for (int jk = tid; jk < NN * NN; jk += 256) {
        const int j = jk >> 5;
        const int k = jk & 31;

        const float dot   = vx[j] * vx[k] + vy[j] * vy[k] + vz[j] * vz[k];
        const float Rij   = drow[j];
        const float Rik   = drow[k];
        const float theta = dot / (Rij * Rik + 1e-5f);
        const float cut   = frow[j] * frow[k];
        const float avg   = (Rij + Rik) * 0.5f;

        float s, c;
        sincosf(theta, &s, &c);

        float ct[4];
        ct[0] = c;
        ct[1] = c * C1 + s * S1;
        ct[2] = c * C2 + s * S2;
        ct[3] = c * C3 + s * S3;

        #pragma unroll
        for (int r = 0; r < 5; ++r) {
            const float dd = avg - RS[r];
            const float w  = cut * expf(-ITA * dd * dd);
            #pragma unroll
            for (int t = 0; t < 4; ++t) {
                const float ap  = 1.f + ct[t];
                const float am  = 1.f - ct[t];
                const float ap2 = ap * ap;
                const float am2 = am * am;
                acc[r * 4 + t]      += w * (ap2 * ap2);   // lambda = +1
                acc[20 + r * 4 + t] += w * (am2 * am2);   // lambda = -1
            }
        }
    }

    // Wave (64-lane) shuffle reduce, then cross-wave via LDS.
    const int lane = tid & 63;
    const int wave = tid >> 6;
    #pragma unroll
    for (int p = 0; p < NP; ++p) {
        float v = acc[p];
        #pragma unroll
        for (int off = 32; off > 0; off >>= 1)
            v += __shfl_down(v, off);
        if (lane == 0) red[wave * NP + p] = v;
    }
    __syncthreads();

    if (tid < NP) {
        const float v = red[tid] + red[NP + tid] + red[2 * NP + tid] + red[3 * NP + tid];
        out[bi * NP + tid] = v * 0.125f;   // 2^(1-zeta) = 0.125
    }
}

extern "C" void kernel_launch(void* const* d_in, const int* in_sizes, int n_in,
                              void* d_out, int out_size, void* d_ws, size_t ws_size,
                              hipStream_t stream) {
    const float* d_cutoff = (const float*)d_in[0];
    const float* d        = (const float*)d_in[1];
    const float* coords   = (const float*)d_in[2];
    float* out            = (float*)d_out;

    // B=16, N=32 -> 512 blocks of 256 threads (one block per (b,i))
    angsym_kernel<<<512, 256, 0, stream>>>(d_cutoff, d, coords, out);
}

// Round 2
// 9.660 us; speedup vs baseline: 1.8090x; 1.8090x over previous
//
#include <hip/hip_runtime.h>
#include <math.h>

#define NN 32   // atoms
#define NP 40   // symmetry params
#define BOHR_D 0.52917721092

__global__ __launch_bounds__(256) void angsym_kernel(
    const float* __restrict__ d_cutoff,   // (B,N,N)
    const float* __restrict__ d,          // (B,N,N)
    const float* __restrict__ coords,     // (B,N,3)
    float* __restrict__ out)              // (B,N,40)
{
    __shared__ float cxyz[NN * 3];
    __shared__ float vx[NN], vy[NN], vz[NN];
    __shared__ float drow[NN], frow[NN];
    __shared__ float red[4 * NP];

    const int bi = blockIdx.x;            // b*32 + i
    const int b  = bi >> 5;
    const int i  = bi & 31;
    const int tid = threadIdx.x;

    if (tid < NN * 3)                cxyz[tid]       = coords[b * NN * 3 + tid];
    if (tid >= 128 && tid < 128+NN)  drow[tid - 128] = d[(b * NN + i) * NN + (tid - 128)];
    if (tid >= 192 && tid < 192+NN)  frow[tid - 192] = d_cutoff[(b * NN + i) * NN + (tid - 192)];
    __syncthreads();

    if (tid < NN) {
        vx[tid] = cxyz[i * 3 + 0] - cxyz[tid * 3 + 0];
        vy[tid] = cxyz[i * 3 + 1] - cxyz[tid * 3 + 1];
        vz[tid] = cxyz[i * 3 + 2] - cxyz[tid * 3 + 2];
    }
    __syncthreads();

    // cos/sin of the f32 theta offsets {1.57f, 3.14f, 4.71f}
    const float C1 = (float)0.00079632671073326442;
    const float S1 = (float)0.99999968293183461;
    const float C2 = (float)-0.99999873172753954;
    const float S2 = (float)0.0015926529164868282;
    const float C3 = (float)-0.0023889083720362966;
    const float S3 = (float)-0.99999714638771537;

    const float RS[5] = {
        (float)(0.5  / BOHR_D),
        (float)(1.17 / BOHR_D),
        (float)(1.83 / BOHR_D),
        (float)(2.5  / BOHR_D),
        (float)(3.17 / BOHR_D)
    };
    const float KE = -1.6158184504300992f;   // -1.12 * log2(e)

    float a[NP];
    #pragma unroll
    for (int p = 0; p < NP; ++p) a[p] = 0.f;

    // Symmetric in (j,k): iterate 528 pairs j<=k, off-diag weighted x2.
    for (int m = tid; m < 528; m += 256) {
        // triangular decode: start(j) = j*(65-j)/2; boundaries are exact
        // (discriminant is the perfect square (65-2j)^2 there).
        const float disc = sqrtf(4225.0f - 8.0f * (float)m);
        const int j = (int)((65.0f - disc) * 0.5f);
        const int k = j + m - (j * (65 - j)) / 2;

        const float dot = vx[j] * vx[k] + vy[j] * vy[k] + vz[j] * vz[k];
        const float Rij = drow[j];
        const float Rik = drow[k];
        const float theta = dot / (Rij * Rik + 1e-5f);   // IEEE div (ref-match)
        float cut = frow[j] * frow[k];
        cut = (j != k) ? cut * 2.0f : cut;
        const float avg = (Rij + Rik) * 0.5f;

        // exact-enough range reduction in f64, then HW sin/cos (revolutions)
        double td = (double)theta * 0.15915494309189535;  // theta / (2*pi)
        td -= floor(td);
        const float rev = (float)td;
        const float s = __builtin_amdgcn_sinf(rev);
        const float c = __builtin_amdgcn_cosf(rev);

        const float ct0 = c;
        const float ct1 = c * C1 + s * S1;
        const float ct2 = c * C2 + s * S2;
        const float ct3 = c * C3 + s * S3;

        float angp[4], angm[4];
        {
            const float cts[4] = {ct0, ct1, ct2, ct3};
            #pragma unroll
            for (int t = 0; t < 4; ++t) {
                const float ap  = 1.f + cts[t];
                const float am  = 1.f - cts[t];
                const float ap2 = ap * ap;
                const float am2 = am * am;
                angp[t] = ap2 * ap2;
                angm[t] = am2 * am2;
            }
        }

        #pragma unroll
        for (int r = 0; r < 5; ++r) {
            const float dd = avg - RS[r];
            const float w  = cut * __builtin_amdgcn_exp2f(KE * dd * dd);
            #pragma unroll
            for (int t = 0; t < 4; ++t) {
                a[r * 4 + t]      += w * angp[t];   // lambda = +1
                a[20 + r * 4 + t] += w * angm[t];   // lambda = -1
            }
        }
    }

    // Split-butterfly reduce: halve the live set at xor 1/2/4, then full
    // reduce of 5 values at xor 8/16/32.  Lane ends holding params
    // [s*5, s*5+5) with s = 4*bit0 + 2*bit1 + 1*bit2 of the lane id.
    const int lane = tid & 63;
    const int wave = tid >> 6;

    #pragma unroll
    for (int m_ = 0; m_ < 20; ++m_) {
        const float plo = a[m_]      + __shfl_xor(a[m_],      1);
        const float phi = a[m_ + 20] + __shfl_xor(a[m_ + 20], 1);
        a[m_] = (lane & 1) ? phi : plo;
    }
    #pragma unroll
    for (int m_ = 0; m_ < 10; ++m_) {
        const float plo = a[m_]      + __shfl_xor(a[m_],      2);
        const float phi = a[m_ + 10] + __shfl_xor(a[m_ + 10], 2);
        a[m_] = (lane & 2) ? phi : plo;
    }
    #pragma unroll
    for (int m_ = 0; m_ < 5; ++m_) {
        const float plo = a[m_]     + __shfl_xor(a[m_],     4);
        const float phi = a[m_ + 5] + __shfl_xor(a[m_ + 5], 4);
        a[m_] = (lane & 4) ? phi : plo;
    }
    #pragma unroll
    for (int m_ = 0; m_ < 5; ++m_) {
        a[m_] += __shfl_xor(a[m_], 8);
        a[m_] += __shfl_xor(a[m_], 16);
        a[m_] += __shfl_xor(a[m_], 32);
    }

    const int s_idx = ((lane & 1) ? 4 : 0) | ((lane & 2) ? 2 : 0) | ((lane & 4) ? 1 : 0);
    if (lane < 8) {
        #pragma unroll
        for (int q = 0; q < 5; ++q)
            red[wave * NP + s_idx * 5 + q] = a[q];
    }
    __syncthreads();

    if (tid < NP) {
        const float v = red[tid] + red[NP + tid] + red[2 * NP + tid] + red[3 * NP + tid];
        out[bi * NP + tid] = v * 0.125f;   // 2^(1-zeta)
    }
}

extern "C" void kernel_launch(void* const* d_in, const int* in_sizes, int n_in,
                              void* d_out, int out_size, void* d_ws, size_t ws_size,
                              hipStream_t stream) {
    const float* d_cutoff = (const float*)d_in[0];
    const float* d        = (const float*)d_in[1];
    const float* coords   = (const float*)d_in[2];
    float* out            = (float*)d_out;

    angsym_kernel<<<512, 256, 0, stream>>>(d_cutoff, d, coords, out);
}